// Round 6
// baseline (217.380 us; speedup 1.0000x reference)
//
#include <hip/hip_runtime.h>

typedef unsigned short ushort_t;
typedef unsigned int uint32;
typedef __bf16 bf16x8 __attribute__((ext_vector_type(8)));
typedef float f32x4 __attribute__((ext_vector_type(4)));
typedef float f4 __attribute__((ext_vector_type(4)));
typedef unsigned short us4 __attribute__((ext_vector_type(4)));

// ---- constants for this problem shape ----
// B=16, QL=1024, KL=1024, QS=512, KS=512, KW=3, PAD=1
// gemm1: M=16384, N=1536, K=512   gemm2 (per b): M=1024, N=1024, K=1536 (3 shifted 512-segs)

__device__ __forceinline__ ushort_t f2bf(float f) {
    uint32 u = __builtin_bit_cast(uint32, f);
    u = (u + 0x7fffu + ((u >> 16) & 1u)) >> 16;  // RNE
    return (ushort_t)u;
}

#define SB0() __builtin_amdgcn_sched_barrier(0)
#define SBAR() __builtin_amdgcn_s_barrier()

#define AS1 __attribute__((address_space(1)))
#define AS3 __attribute__((address_space(3)))

// ---------------- fused prep ----------------
__global__ __launch_bounds__(256) void prep_all(const float* __restrict__ q,
                                                const float* __restrict__ Wb,
                                                const float* __restrict__ bb,
                                                const float* __restrict__ k,
                                                const float* __restrict__ Wk,
                                                const float* __restrict__ bk,
                                                ushort_t* __restrict__ qb,
                                                float* __restrict__ biasw,
                                                ushort_t* __restrict__ kbp,
                                                ushort_t* __restrict__ wkb,
                                                float* __restrict__ bkp) {
    const int tid = threadIdx.x;
    if (blockIdx.x < 4096) {
        const int lane = tid & 63, wid = tid >> 6;
        const int m = blockIdx.x * 4 + wid;
        const float* qrow = q + (size_t)m * 512;

        f4 v0 = *(const f4*)(qrow + lane * 4);
        f4 v1 = *(const f4*)(qrow + 256 + lane * 4);
        f4 w0 = *(const f4*)(Wb + lane * 4);
        f4 w1 = *(const f4*)(Wb + 256 + lane * 4);

        float dot = v0[0]*w0[0] + v0[1]*w0[1] + v0[2]*w0[2] + v0[3]*w0[3]
                  + v1[0]*w1[0] + v1[1]*w1[1] + v1[2]*w1[2] + v1[3]*w1[3];

        us4 o0, o1;
        o0[0]=f2bf(v0[0]); o0[1]=f2bf(v0[1]); o0[2]=f2bf(v0[2]); o0[3]=f2bf(v0[3]);
        o1[0]=f2bf(v1[0]); o1[1]=f2bf(v1[1]); o1[2]=f2bf(v1[2]); o1[3]=f2bf(v1[3]);
        *(us4*)(qb + (size_t)m * 512 + lane * 4) = o0;
        *(us4*)(qb + (size_t)m * 512 + 256 + lane * 4) = o1;

        #pragma unroll
        for (int off = 32; off >= 1; off >>= 1) dot += __shfl_xor(dot, off);
        if (lane == 0) biasw[m] = dot + bb[0];
        return;
    }
    const int gid = (blockIdx.x - 4096) * 256 + tid;
    if (gid < 1536) bkp[gid] = bk[(gid & 511) * 3 + (gid >> 9)];

    const int KG = (16 * 1024 * 512) / 4;
    const int PG = (16 * 2 * 512) / 4;

    if (gid < KG) {
        const int e = gid * 4;
        const int b = e >> 19;
        const int rem = e & ((1 << 19) - 1);
        const int row = rem >> 9, c = rem & 511;
        f4 v = *(const f4*)(k + e);
        us4 o; o[0]=f2bf(v[0]); o[1]=f2bf(v[1]); o[2]=f2bf(v[2]); o[3]=f2bf(v[3]);
        *(us4*)(kbp + ((size_t)b * 1026 + row + 1) * 512 + c) = o;
    } else if (gid < KG + PG) {
        const int p = gid - KG;
        const int b = p >> 8, off = p & 255;
        const int row = (off < 128) ? 0 : 1025;
        const int c = (off & 127) * 4;
        us4 z; z[0]=0; z[1]=0; z[2]=0; z[3]=0;
        *(us4*)(kbp + ((size_t)b * 1026 + row) * 512 + c) = z;
    } else {
        const int w = gid - KG - PG;
        const int n = w >> 7;
        const int c = (w & 127) * 4;
        const int o = (n & 511) * 3 + (n >> 9);
        f4 v = *(const f4*)(Wk + (size_t)o * 512 + c);
        us4 ov; ov[0]=f2bf(v[0]); ov[1]=f2bf(v[1]); ov[2]=f2bf(v[2]); ov[3]=f2bf(v[3]);
        *(us4*)(wkb + (size_t)n * 512 + c) = ov;
    }
}

// ---- staging: one K-half panel = rows x 64B, linear in LDS, col-swizzled on global src.
// LDS[row][s] = G[row][s ^ ((row>>1)&3)]; reader XORs the same (involution).
template<int NINST>
__device__ __forceinline__ void stage_half(const char* base, int ld, char* dst, int tid) {
    #pragma unroll
    for (int inst = 0; inst < NINST; ++inst) {
        const int idx = inst * 512 + tid;
        const int row = idx >> 2;
        const int scol = ((idx & 3) ^ ((row >> 1) & 3)) << 4;
        __builtin_amdgcn_global_load_lds(
            (const AS1 void*)(base + (size_t)row * (size_t)ld + scol),
            (AS3 void*)(dst + (size_t)(inst * 512 + (tid & ~63)) * 16),
            16, 0, 0);
    }
}

// NM x 4 MFMA cluster on pre-loaded fragments, acc rows r0..r0+NM-1
#define MFMA_BLK(af, bf, r0, NM)                                             \
    SB0();                                                                   \
    __builtin_amdgcn_s_setprio(1);                                           \
    _Pragma("unroll")                                                        \
    for (int i_ = 0; i_ < (NM); ++i_)                                        \
        _Pragma("unroll")                                                    \
        for (int j_ = 0; j_ < 4; ++j_)                                       \
            acc[(r0) + i_][j_] = __builtin_amdgcn_mfma_f32_16x16x32_bf16(    \
                af[i_], bf[j_], acc[(r0) + i_][j_], 0, 0, 0);                \
    __builtin_amdgcn_s_setprio(0);                                           \
    SB0();

#define VMCNT(n) asm volatile("s_waitcnt vmcnt(" #n ")" ::: "memory")

// gemm1: 128x256 tile, BK=64, 8 waves (2x4), per-wave 64x64. 3 LDS buffers (48KB each).
// Pipelined: each phase reads NEXT phase's frags; MFMA on frags read one phase ago.
// Per buf: Ah0@0(8K) Ah1@8192 Bh0@16384(16K) Bh1@32768.
__global__ __launch_bounds__(512, 2) void gemm1(const ushort_t* __restrict__ qb,
                                                const ushort_t* __restrict__ wkb,
                                                const float* __restrict__ bkp,
                                                ushort_t* __restrict__ coef) {
    __shared__ alignas(16) char lds[147456];
    const int tid = threadIdx.x;
    const int l = tid & 63, wid = tid >> 6;
    const int wr = wid >> 2, wc = wid & 3;       // 2 x 4 wave grid
    int bid = blockIdx.x;
    bid = (bid & 7) * 96 + (bid >> 3);           // XCD swizzle, 768 = 8*96
    const int mt = bid & 127, nt = bid >> 7;     // 128 m-tiles x 6 n-tiles
    const int mbase = mt * 128, nbase = nt * 256;

    const char* Ag = (const char*)(qb + (size_t)mbase * 512);
    const char* Bg = (const char*)(wkb + (size_t)nbase * 512);

    const int r15 = l & 15, q = l >> 4;
    const int swz = ((q ^ (r15 >> 1)) & 3) << 4;
    const int laneA = (wr * 64 + r15) * 64 + swz;
    const int laneB = (wc * 64 + r15) * 64 + swz;

    f32x4 acc[4][4];
    #pragma unroll
    for (int mi = 0; mi < 4; ++mi)
        #pragma unroll
        for (int ni = 0; ni < 4; ++ni)
            #pragma unroll
            for (int r = 0; r < 4; ++r) acc[mi][ni][r] = 0.f;

    // prologue: stage tiles 0 and 1 fully (h0 then h1 each)
    stage_half<1>(Ag, 1024, lds, tid);
    stage_half<2>(Bg, 1024, lds + 16384, tid);
    stage_half<1>(Ag + 64, 1024, lds + 8192, tid);
    stage_half<2>(Bg + 64, 1024, lds + 32768, tid);
    stage_half<1>(Ag + 128, 1024, lds + 49152, tid);
    stage_half<2>(Bg + 128, 1024, lds + 49152 + 16384, tid);
    stage_half<1>(Ag + 192, 1024, lds + 49152 + 8192, tid);
    stage_half<2>(Bg + 192, 1024, lds + 49152 + 32768, tid);
    VMCNT(9);                      // tile0.h0 landed
    SBAR();
    bf16x8 Aa[2], Ab[2], Ba[4], Bb[4];
    #pragma unroll
    for (int i = 0; i < 2; ++i) Aa[i] = *(const bf16x8*)(lds + laneA + i * 1024);
    #pragma unroll
    for (int j = 0; j < 4; ++j) Ba[j] = *(const bf16x8*)(lds + 16384 + laneB + j * 1024);

    for (int t = 0; t < 8; ++t) {
        const char* R  = lds + (t % 3) * 49152;
        const char* Nx = lds + ((t + 1) % 3) * 49152;
        char* W        = lds + ((t + 2) % 3) * 49152;
        const int tn2 = (t + 2 < 8) ? t + 2 : 7;
        const size_t off2 = (size_t)tn2 * 128;

        // P0: read kk0.mihi; WAR-guard barrier; MFMA kk0 x milo
        #pragma unroll
        for (int i = 0; i < 2; ++i) Ab[i] = *(const bf16x8*)(R + laneA + (2 + i) * 1024);
        SB0(); SBAR();
        MFMA_BLK(Aa, Ba, 0, 2)

        // P1: stage W.h0; vmcnt -> (t+1 needs, one-ahead) ; barrier; read kk1.milo + B.kk1; MFMA kk0 x mihi
        stage_half<1>(Ag + off2, 1024, W, tid);
        stage_half<2>(Bg + off2, 1024, W + 16384, tid);
        VMCNT(6);
        SBAR(); SB0();
        #pragma unroll
        for (int i = 0; i < 2; ++i) Aa[i] = *(const bf16x8*)(R + 8192 + laneA + i * 1024);
        #pragma unroll
        for (int j = 0; j < 4; ++j) Bb[j] = *(const bf16x8*)(R + 32768 + laneB + j * 1024);
        MFMA_BLK(Ab, Ba, 2, 2)

        // P2: stage W.h1; read kk1.mihi; MFMA kk1 x milo (no barrier needed)
        stage_half<1>(Ag + off2 + 64, 1024, W + 8192, tid);
        stage_half<2>(Bg + off2 + 64, 1024, W + 32768, tid);
        #pragma unroll
        for (int i = 0; i < 2; ++i) Ab[i] = *(const bf16x8*)(R + 8192 + laneA + (2 + i) * 1024);
        MFMA_BLK(Aa, Bb, 0, 2)

        // P3: vmcnt -> next tile h0 ready; barrier; read next.kk0; MFMA kk1 x mihi
        VMCNT(6);
        SBAR(); SB0();
        #pragma unroll
        for (int i = 0; i < 2; ++i) Aa[i] = *(const bf16x8*)(Nx + laneA + i * 1024);
        #pragma unroll
        for (int j = 0; j < 4; ++j) Ba[j] = *(const bf16x8*)(Nx + 16384 + laneB + j * 1024);
        MFMA_BLK(Ab, Bb, 2, 2)
    }

    #pragma unroll
    for (int ni = 0; ni < 4; ++ni) {
        const int ncol = nbase + wc * 64 + ni * 16 + r15;
        const float bkv = bkp[ncol];
        #pragma unroll
        for (int mi = 0; mi < 4; ++mi) {
            const int mrow0 = mbase + wr * 64 + mi * 16 + q * 4;
            #pragma unroll
            for (int r = 0; r < 4; ++r)
                coef[(size_t)(mrow0 + r) * 1536 + ncol] = f2bf(acc[mi][ni][r] + bkv);
        }
    }
}

// gemm2: 256x256 tile, BK=64, 8 waves (2x4), per-wave 128x64. LDS 2x64KB dbuf.
// Pipelined 4 phases/K-tile, 16 MFMA each; frags read one phase ahead; 3 barriers/tile.
// Per buf: Ah0@0(16K) Ah1@16384 Bh0@32768 Bh1@49152.
__global__ __launch_bounds__(512, 2) void gemm2(const ushort_t* __restrict__ coef,
                                                const ushort_t* __restrict__ kbp,
                                                const float* __restrict__ biasw,
                                                const float* __restrict__ bias_b,
                                                float* __restrict__ out) {
    __shared__ alignas(16) char lds[131072];
    const int tid = threadIdx.x;
    const int l = tid & 63, wid = tid >> 6;
    const int wr = wid >> 2, wc = wid & 3;
    int bid = blockIdx.x;
    bid = (bid & 7) * 32 + (bid >> 3);           // XCD swizzle, 256 = 8*32
    const int jt = bid & 3, it = (bid >> 2) & 3, b = bid >> 4;
    const int ibase = it * 256, jbase = jt * 256;

    const char* Ag = (const char*)(coef + ((size_t)b * 1024 + ibase) * 1536);
    const char* Bg = (const char*)(kbp + ((size_t)b * 1026 + jbase) * 512);

    const int r15 = l & 15, q = l >> 4;
    const int swz = ((q ^ (r15 >> 1)) & 3) << 4;
    const int laneA = (wr * 128 + r15) * 64 + swz;
    const int laneB = (wc * 64 + r15) * 64 + swz;

    f32x4 acc[8][4];
    #pragma unroll
    for (int mi = 0; mi < 8; ++mi)
        #pragma unroll
        for (int ni = 0; ni < 4; ++ni)
            #pragma unroll
            for (int r = 0; r < 4; ++r) acc[mi][ni][r] = 0.f;

    // prologue: full tile 0 (h0 pair then h1 pair), wait oldest 4 (Ah0,Bh0)
    stage_half<2>(Ag, 3072, lds, tid);
    stage_half<2>(Bg, 1024, lds + 32768, tid);
    stage_half<2>(Ag + 64, 3072, lds + 16384, tid);
    stage_half<2>(Bg + 64, 1024, lds + 49152, tid);
    VMCNT(4);
    SBAR();
    bf16x8 Aa[4], Ab[4], Ba[4], Bb[4];
    #pragma unroll
    for (int i = 0; i < 4; ++i) Aa[i] = *(const bf16x8*)(lds + laneA + i * 1024);
    #pragma unroll
    for (int j = 0; j < 4; ++j) Ba[j] = *(const bf16x8*)(lds + 32768 + laneB + j * 1024);

    for (int t = 0; t < 24; ++t) {
        const char* R = lds + ((t & 1) << 16);
        char* W       = lds + (((t + 1) & 1) << 16);
        const int tn = (t < 23) ? t + 1 : t;
        const size_t aoff = (size_t)tn * 128;
        const size_t boff = (size_t)(tn >> 3) * 1024 + (size_t)(tn & 7) * 128;

        // P0: read kk0.mihi; WAR-guard barrier; MFMA kk0 x milo
        #pragma unroll
        for (int i = 0; i < 4; ++i) Ab[i] = *(const bf16x8*)(R + laneA + (4 + i) * 1024);
        SB0(); SBAR();
        MFMA_BLK(Aa, Ba, 0, 4)

        // P1: stage W.h0; vmcnt(4) -> R.h1 landed; barrier; read kk1.milo + B.kk1; MFMA kk0 x mihi
        stage_half<2>(Ag + aoff, 3072, W, tid);
        stage_half<2>(Bg + boff, 1024, W + 32768, tid);
        VMCNT(4);
        SBAR(); SB0();
        #pragma unroll
        for (int i = 0; i < 4; ++i) Aa[i] = *(const bf16x8*)(R + 16384 + laneA + i * 1024);
        #pragma unroll
        for (int j = 0; j < 4; ++j) Bb[j] = *(const bf16x8*)(R + 49152 + laneB + j * 1024);
        MFMA_BLK(Ab, Ba, 4, 4)

        // P2: stage W.h1; read kk1.mihi; MFMA kk1 x milo (no barrier)
        stage_half<2>(Ag + aoff + 64, 3072, W + 16384, tid);
        stage_half<2>(Bg + boff + 64, 1024, W + 49152, tid);
        #pragma unroll
        for (int i = 0; i < 4; ++i) Ab[i] = *(const bf16x8*)(R + 16384 + laneA + (4 + i) * 1024);
        MFMA_BLK(Aa, Bb, 0, 4)

        // P3: vmcnt(4) -> W.h0 landed; barrier; read next tile kk0; MFMA kk1 x mihi
        VMCNT(4);
        SBAR(); SB0();
        #pragma unroll
        for (int i = 0; i < 4; ++i) Aa[i] = *(const bf16x8*)(W + laneA + i * 1024);
        #pragma unroll
        for (int j = 0; j < 4; ++j) Ba[j] = *(const bf16x8*)(W + 32768 + laneB + j * 1024);
        MFMA_BLK(Ab, Bb, 4, 4)
    }

    const float bb0v = bias_b[0];
    #pragma unroll
    for (int mi = 0; mi < 8; ++mi) {
        const int irow0 = ibase + wr * 128 + mi * 16 + q * 4;
        #pragma unroll
        for (int r = 0; r < 4; ++r) {
            const float bv = biasw[b * 1024 + irow0 + r] + bb0v;
            #pragma unroll
            for (int ni = 0; ni < 4; ++ni) {
                const int jcol = jbase + wc * 64 + ni * 16 + r15;
                out[((size_t)b << 20) + (size_t)(irow0 + r) * 1024 + jcol] = acc[mi][ni][r] + bv;
            }
        }
    }
}

extern "C" void kernel_launch(void* const* d_in, const int* in_sizes, int n_in,
                              void* d_out, int out_size, void* d_ws, size_t ws_size,
                              hipStream_t stream) {
    const float* q      = (const float*)d_in[0];
    const float* k      = (const float*)d_in[1];
    const float* Wk     = (const float*)d_in[2];
    const float* bk     = (const float*)d_in[3];
    const float* Wb     = (const float*)d_in[4];
    const float* bb     = (const float*)d_in[5];
    const float* bias_b = (const float*)d_in[6];
    float* out = (float*)d_out;

    ushort_t* ws   = (ushort_t*)d_ws;
    ushort_t* qb   = ws;
    ushort_t* kbp  = qb  + (size_t)16384 * 512;
    ushort_t* wkb  = kbp + (size_t)16 * 1026 * 512;
    ushort_t* coef = wkb + (size_t)1536 * 512;
    float*    biasw = (float*)(coef + (size_t)16384 * 1536);
    float*    bkp   = biasw + 16384;

    prep_all<<<13072, 256, 0, stream>>>(q, Wb, bb, k, Wk, bk, qb, biasw, kbp, wkb, bkp);
    gemm1<<<768, 512, 0, stream>>>(qb, wkb, bkp, coef);
    gemm2<<<256, 512, 0, stream>>>(coef, kbp, biasw, bias_b, out);
}

// Round 7
// 211.797 us; speedup vs baseline: 1.0264x; 1.0264x over previous
//
#include <hip/hip_runtime.h>

typedef unsigned short ushort_t;
typedef unsigned int uint32;
typedef __bf16 bf16x8 __attribute__((ext_vector_type(8)));
typedef float f32x4 __attribute__((ext_vector_type(4)));
typedef float f4 __attribute__((ext_vector_type(4)));
typedef unsigned short us4 __attribute__((ext_vector_type(4)));

// ---- constants for this problem shape ----
// B=16, QL=1024, KL=1024, QS=512, KS=512, KW=3, PAD=1
// gemm1: M=16384, N=1536, K=512   gemm2 (per b): M=1024, N=1024, K=1536 (3 shifted 512-segs)

__device__ __forceinline__ ushort_t f2bf(float f) {
    uint32 u = __builtin_bit_cast(uint32, f);
    u = (u + 0x7fffu + ((u >> 16) & 1u)) >> 16;  // RNE
    return (ushort_t)u;
}

#define SB0() __builtin_amdgcn_sched_barrier(0)
#define SBAR() __builtin_amdgcn_s_barrier()
#define VMCNT(n) asm volatile("s_waitcnt vmcnt(" #n ")" ::: "memory")
// post-barrier drain of own ds_reads, order-pinned (rule #18)
#define LGKM0_SB() do { asm volatile("s_waitcnt lgkmcnt(0)" ::: "memory"); SB0(); } while (0)

#define AS1 __attribute__((address_space(1)))
#define AS3 __attribute__((address_space(3)))

// ---------------- fused prep ----------------
__global__ __launch_bounds__(256) void prep_all(const float* __restrict__ q,
                                                const float* __restrict__ Wb,
                                                const float* __restrict__ bb,
                                                const float* __restrict__ k,
                                                const float* __restrict__ Wk,
                                                const float* __restrict__ bk,
                                                ushort_t* __restrict__ qb,
                                                float* __restrict__ biasw,
                                                ushort_t* __restrict__ kbp,
                                                ushort_t* __restrict__ wkb,
                                                float* __restrict__ bkp) {
    const int tid = threadIdx.x;
    if (blockIdx.x < 4096) {
        const int lane = tid & 63, wid = tid >> 6;
        const int m = blockIdx.x * 4 + wid;
        const float* qrow = q + (size_t)m * 512;

        f4 v0 = *(const f4*)(qrow + lane * 4);
        f4 v1 = *(const f4*)(qrow + 256 + lane * 4);
        f4 w0 = *(const f4*)(Wb + lane * 4);
        f4 w1 = *(const f4*)(Wb + 256 + lane * 4);

        float dot = v0[0]*w0[0] + v0[1]*w0[1] + v0[2]*w0[2] + v0[3]*w0[3]
                  + v1[0]*w1[0] + v1[1]*w1[1] + v1[2]*w1[2] + v1[3]*w1[3];

        us4 o0, o1;
        o0[0]=f2bf(v0[0]); o0[1]=f2bf(v0[1]); o0[2]=f2bf(v0[2]); o0[3]=f2bf(v0[3]);
        o1[0]=f2bf(v1[0]); o1[1]=f2bf(v1[1]); o1[2]=f2bf(v1[2]); o1[3]=f2bf(v1[3]);
        *(us4*)(qb + (size_t)m * 512 + lane * 4) = o0;
        *(us4*)(qb + (size_t)m * 512 + 256 + lane * 4) = o1;

        #pragma unroll
        for (int off = 32; off >= 1; off >>= 1) dot += __shfl_xor(dot, off);
        if (lane == 0) biasw[m] = dot + bb[0];
        return;
    }
    const int gid = (blockIdx.x - 4096) * 256 + tid;
    if (gid < 1536) bkp[gid] = bk[(gid & 511) * 3 + (gid >> 9)];

    const int KG = (16 * 1024 * 512) / 4;
    const int PG = (16 * 2 * 512) / 4;

    if (gid < KG) {
        const int e = gid * 4;
        const int b = e >> 19;
        const int rem = e & ((1 << 19) - 1);
        const int row = rem >> 9, c = rem & 511;
        f4 v = *(const f4*)(k + e);
        us4 o; o[0]=f2bf(v[0]); o[1]=f2bf(v[1]); o[2]=f2bf(v[2]); o[3]=f2bf(v[3]);
        *(us4*)(kbp + ((size_t)b * 1026 + row + 1) * 512 + c) = o;
    } else if (gid < KG + PG) {
        const int p = gid - KG;
        const int b = p >> 8, off = p & 255;
        const int row = (off < 128) ? 0 : 1025;
        const int c = (off & 127) * 4;
        us4 z; z[0]=0; z[1]=0; z[2]=0; z[3]=0;
        *(us4*)(kbp + ((size_t)b * 1026 + row) * 512 + c) = z;
    } else {
        const int w = gid - KG - PG;
        const int n = w >> 7;
        const int c = (w & 127) * 4;
        const int o = (n & 511) * 3 + (n >> 9);
        f4 v = *(const f4*)(Wk + (size_t)o * 512 + c);
        us4 ov; ov[0]=f2bf(v[0]); ov[1]=f2bf(v[1]); ov[2]=f2bf(v[2]); ov[3]=f2bf(v[3]);
        *(us4*)(wkb + (size_t)n * 512 + c) = ov;
    }
}

// ---- staging: one K-half panel = rows x 64B, linear in LDS, col-swizzled on global src.
// LDS[row][s] = G[row][s ^ ((row>>1)&3)]; reader XORs the same (involution). 0 conflicts (r2-r6).
template<int NINST>
__device__ __forceinline__ void stage_half(const char* base, int ld, char* dst, int tid) {
    #pragma unroll
    for (int inst = 0; inst < NINST; ++inst) {
        const int idx = inst * 512 + tid;
        const int row = idx >> 2;
        const int scol = ((idx & 3) ^ ((row >> 1) & 3)) << 4;
        __builtin_amdgcn_global_load_lds(
            (const AS1 void*)(base + (size_t)row * (size_t)ld + scol),
            (AS3 void*)(dst + (size_t)(inst * 512 + (tid & ~63)) * 16),
            16, 0, 0);
    }
}

// gemm2 cluster: 8 mi x 2 nj = 16 MFMA
#define CLUSTER16_G2(AF, BF, njb)                                            \
    __builtin_amdgcn_s_setprio(1);                                           \
    _Pragma("unroll")                                                        \
    for (int i_ = 0; i_ < 8; ++i_)                                           \
        _Pragma("unroll")                                                    \
        for (int j_ = 0; j_ < 2; ++j_)                                       \
            acc[i_][(njb) + j_] = __builtin_amdgcn_mfma_f32_16x16x32_bf16(   \
                AF[i_], BF[j_], acc[i_][(njb) + j_], 0, 0, 0);               \
    __builtin_amdgcn_s_setprio(0);                                           \
    SB0();

// gemm1 cluster: 4 mi x 4 nj = 16 MFMA
#define CLUSTER16_G1(AF, BF)                                                 \
    __builtin_amdgcn_s_setprio(1);                                           \
    _Pragma("unroll")                                                        \
    for (int i_ = 0; i_ < 4; ++i_)                                           \
        _Pragma("unroll")                                                    \
        for (int j_ = 0; j_ < 4; ++j_)                                       \
            acc[i_][j_] = __builtin_amdgcn_mfma_f32_16x16x32_bf16(           \
                AF[i_], BF[j_], acc[i_][j_], 0, 0, 0);                       \
    __builtin_amdgcn_s_setprio(0);                                           \
    SB0();

// gemm1: 128x256 tile, BK=64, 8 waves (2x4), per-wave 64x64. 3 LDS bufs x 48KB.
// Per buf: Ah0@0(8K) Ah1@8192 Bh0@16384(16K) Bh1@32768. 2 phases/tile (kk0, kk1),
// 16 MFMA each; stage t+2 one K-half per phase; vmcnt(9) per phase, lead >= 2 phases.
__global__ __launch_bounds__(512, 2) void gemm1(const ushort_t* __restrict__ qb,
                                                const ushort_t* __restrict__ wkb,
                                                const float* __restrict__ bkp,
                                                ushort_t* __restrict__ coef) {
    __shared__ alignas(16) char lds[147456];
    const int tid = threadIdx.x;
    const int l = tid & 63, wid = tid >> 6;
    const int wr = wid >> 2, wc = wid & 3;       // 2 x 4 wave grid
    int bid = blockIdx.x;
    bid = (bid & 7) * 96 + (bid >> 3);           // XCD swizzle, 768 = 8*96
    const int mt = bid & 127, nt = bid >> 7;     // 128 m-tiles x 6 n-tiles
    const int mbase = mt * 128, nbase = nt * 256;

    const char* Ag = (const char*)(qb + (size_t)mbase * 512);
    const char* Bg = (const char*)(wkb + (size_t)nbase * 512);

    const int r15 = l & 15, q = l >> 4;
    const int swz = ((q ^ (r15 >> 1)) & 3) << 4;
    const int laneA = (wr * 64 + r15) * 64 + swz;
    const int laneB = (wc * 64 + r15) * 64 + swz;

    f32x4 acc[4][4];
    #pragma unroll
    for (int mi = 0; mi < 4; ++mi)
        #pragma unroll
        for (int ni = 0; ni < 4; ++ni)
            #pragma unroll
            for (int r = 0; r < 4; ++r) acc[mi][ni][r] = 0.f;

    // prologue: stage tiles 0 and 1 fully (per phase-need order: h0 then h1)
    stage_half<1>(Ag, 1024, lds, tid);
    stage_half<2>(Bg, 1024, lds + 16384, tid);
    stage_half<1>(Ag + 64, 1024, lds + 8192, tid);
    stage_half<2>(Bg + 64, 1024, lds + 32768, tid);
    stage_half<1>(Ag + 128, 1024, lds + 49152, tid);
    stage_half<2>(Bg + 128, 1024, lds + 49152 + 16384, tid);
    stage_half<1>(Ag + 192, 1024, lds + 49152 + 8192, tid);
    stage_half<2>(Bg + 192, 1024, lds + 49152 + 32768, tid);
    VMCNT(9);                      // tile0.h0 landed (12 outstanding -> 9)
    SBAR(); SB0();

    for (int t = 0; t < 8; ++t) {
        const char* R = lds + (t % 3) * 49152;
        char* W       = lds + ((t + 2) % 3) * 49152;
        const int tn2 = (t + 2 < 8) ? t + 2 : 7;
        const size_t off2 = (size_t)tn2 * 128;

        bf16x8 A0[4], B0[4];
        // ---- P1: kk0 (reads 8); stage t+2.h0; vmcnt(9) -> t.h1 landed
        #pragma unroll
        for (int i = 0; i < 4; ++i) A0[i] = *(const bf16x8*)(R + laneA + i * 1024);
        #pragma unroll
        for (int j = 0; j < 4; ++j) B0[j] = *(const bf16x8*)(R + 16384 + laneB + j * 1024);
        stage_half<1>(Ag + off2, 1024, W, tid);
        stage_half<2>(Bg + off2, 1024, W + 16384, tid);
        VMCNT(9);
        SBAR();
        LGKM0_SB();
        CLUSTER16_G1(A0, B0)

        // ---- P2: kk1 (reads 8); stage t+2.h1; vmcnt(9) -> (t+1).h0 landed
        #pragma unroll
        for (int i = 0; i < 4; ++i) A0[i] = *(const bf16x8*)(R + 8192 + laneA + i * 1024);
        #pragma unroll
        for (int j = 0; j < 4; ++j) B0[j] = *(const bf16x8*)(R + 32768 + laneB + j * 1024);
        stage_half<1>(Ag + off2 + 64, 1024, W + 8192, tid);
        stage_half<2>(Bg + off2 + 64, 1024, W + 32768, tid);
        VMCNT(9);
        SBAR();
        LGKM0_SB();
        CLUSTER16_G1(A0, B0)
    }

    #pragma unroll
    for (int ni = 0; ni < 4; ++ni) {
        const int ncol = nbase + wc * 64 + ni * 16 + r15;
        const float bkv = bkp[ncol];
        #pragma unroll
        for (int mi = 0; mi < 4; ++mi) {
            const int mrow0 = mbase + wr * 64 + mi * 16 + q * 4;
            #pragma unroll
            for (int r = 0; r < 4; ++r)
                coef[(size_t)(mrow0 + r) * 1536 + ncol] = f2bf(acc[mi][ni][r] + bkv);
        }
    }
}

// gemm2: 256x256 tile, BK=64, 8 waves (2x4), per-wave 128x64. LDS 2x64KB dbuf.
// Per buf: Ah0@0(16K) Ah1@16384 Bh0@32768 Bh1@49152.
// 4 phases/tile (kk x nj-half), 16 MFMA each, reads 10/2/10/2; stage one half per
// phase in need-order [Ah0,Bh0,Ah1,Bh1]; vmcnt(4) at P2 (t.h1 ready) and P4
// ((t+1).h0 ready) — every wait lands 2-3 phases after its loads' issue.
__global__ __launch_bounds__(512, 2) void gemm2(const ushort_t* __restrict__ coef,
                                                const ushort_t* __restrict__ kbp,
                                                const float* __restrict__ biasw,
                                                const float* __restrict__ bias_b,
                                                float* __restrict__ out) {
    __shared__ alignas(16) char lds[131072];
    const int tid = threadIdx.x;
    const int l = tid & 63, wid = tid >> 6;
    const int wr = wid >> 2, wc = wid & 3;
    int bid = blockIdx.x;
    bid = (bid & 7) * 32 + (bid >> 3);           // XCD swizzle, 256 = 8*32
    const int jt = bid & 3, it = (bid >> 2) & 3, b = bid >> 4;
    const int ibase = it * 256, jbase = jt * 256;

    const char* Ag = (const char*)(coef + ((size_t)b * 1024 + ibase) * 1536);
    const char* Bg = (const char*)(kbp + ((size_t)b * 1026 + jbase) * 512);

    const int r15 = l & 15, q = l >> 4;
    const int swz = ((q ^ (r15 >> 1)) & 3) << 4;
    const int laneA = (wr * 128 + r15) * 64 + swz;
    const int laneB = (wc * 64 + r15) * 64 + swz;

    f32x4 acc[8][4];
    #pragma unroll
    for (int mi = 0; mi < 8; ++mi)
        #pragma unroll
        for (int ni = 0; ni < 4; ++ni)
            #pragma unroll
            for (int r = 0; r < 4; ++r) acc[mi][ni][r] = 0.f;

    // prologue: stage tile 0 in need-order [Ah0,Bh0,Ah1,Bh1]; wait oldest 4
    stage_half<2>(Ag, 3072, lds, tid);
    stage_half<2>(Bg, 1024, lds + 32768, tid);
    stage_half<2>(Ag + 64, 3072, lds + 16384, tid);
    stage_half<2>(Bg + 64, 1024, lds + 49152, tid);
    VMCNT(4);
    SBAR(); SB0();

    for (int t = 0; t < 24; ++t) {
        const char* R = lds + ((t & 1) << 16);
        char* W       = lds + (((t + 1) & 1) << 16);
        const int tn = (t < 23) ? t + 1 : t;
        const size_t aoff = (size_t)tn * 128;
        const size_t boff = (size_t)(tn >> 3) * 1024 + (size_t)(tn & 7) * 128;

        bf16x8 A0[8], B0[2], B1[2];
        // ---- P1: kk0, nj 0-1 (reads 10); stage (t+1).Ah0
        #pragma unroll
        for (int i = 0; i < 8; ++i) A0[i] = *(const bf16x8*)(R + laneA + i * 1024);
        B0[0] = *(const bf16x8*)(R + 32768 + laneB);
        B0[1] = *(const bf16x8*)(R + 32768 + laneB + 1024);
        stage_half<2>(Ag + aoff, 3072, W, tid);
        SBAR();
        LGKM0_SB();
        CLUSTER16_G2(A0, B0, 0)

        // ---- P2: kk0, nj 2-3 (reads 2); stage (t+1).Bh0; vmcnt(4) -> t.h1 landed
        B1[0] = *(const bf16x8*)(R + 32768 + laneB + 2048);
        B1[1] = *(const bf16x8*)(R + 32768 + laneB + 3072);
        stage_half<2>(Bg + boff, 1024, W + 32768, tid);
        VMCNT(4);
        SBAR();
        LGKM0_SB();
        CLUSTER16_G2(A0, B1, 2)

        // ---- P3: kk1, nj 0-1 (reads 10); stage (t+1).Ah1
        #pragma unroll
        for (int i = 0; i < 8; ++i) A0[i] = *(const bf16x8*)(R + 16384 + laneA + i * 1024);
        B0[0] = *(const bf16x8*)(R + 49152 + laneB);
        B0[1] = *(const bf16x8*)(R + 49152 + laneB + 1024);
        stage_half<2>(Ag + aoff + 64, 3072, W + 16384, tid);
        SBAR();
        LGKM0_SB();
        CLUSTER16_G2(A0, B0, 0)

        // ---- P4: kk1, nj 2-3 (reads 2); stage (t+1).Bh1; vmcnt(4) -> (t+1).h0 landed
        B1[0] = *(const bf16x8*)(R + 49152 + laneB + 2048);
        B1[1] = *(const bf16x8*)(R + 49152 + laneB + 3072);
        stage_half<2>(Bg + boff + 64, 1024, W + 49152, tid);
        VMCNT(4);
        SBAR();
        LGKM0_SB();
        CLUSTER16_G2(A0, B1, 2)
    }

    const float bb0v = bias_b[0];
    #pragma unroll
    for (int mi = 0; mi < 8; ++mi) {
        const int irow0 = ibase + wr * 128 + mi * 16 + q * 4;
        #pragma unroll
        for (int r = 0; r < 4; ++r) {
            const float bv = biasw[b * 1024 + irow0 + r] + bb0v;
            #pragma unroll
            for (int ni = 0; ni < 4; ++ni) {
                const int jcol = jbase + wc * 64 + ni * 16 + r15;
                out[((size_t)b << 20) + (size_t)(irow0 + r) * 1024 + jcol] = acc[mi][ni][r] + bv;
            }
        }
    }
}

extern "C" void kernel_launch(void* const* d_in, const int* in_sizes, int n_in,
                              void* d_out, int out_size, void* d_ws, size_t ws_size,
                              hipStream_t stream) {
    const float* q      = (const float*)d_in[0];
    const float* k      = (const float*)d_in[1];
    const float* Wk     = (const float*)d_in[2];
    const float* bk     = (const float*)d_in[3];
    const float* Wb     = (const float*)d_in[4];
    const float* bb     = (const float*)d_in[5];
    const float* bias_b = (const float*)d_in[6];
    float* out = (float*)d_out;

    ushort_t* ws   = (ushort_t*)d_ws;
    ushort_t* qb   = ws;
    ushort_t* kbp  = qb  + (size_t)16384 * 512;
    ushort_t* wkb  = kbp + (size_t)16 * 1026 * 512;
    ushort_t* coef = wkb + (size_t)1536 * 512;
    float*    biasw = (float*)(coef + (size_t)16384 * 1536);
    float*    bkp   = biasw + 16384;

    prep_all<<<13072, 256, 0, stream>>>(q, Wb, bb, k, Wk, bk, qb, biasw, kbp, wkb, bkp);
    gemm1<<<768, 512, 0, stream>>>(qb, wkb, bkp, coef);
    gemm2<<<256, 512, 0, stream>>>(coef, kbp, biasw, bias_b, out);
}